// Round 2
// baseline (4195.251 us; speedup 1.0000x reference)
//
#include <hip/hip_runtime.h>

#define HW 16384
#define W_IMG 128
#define CH 192
#define CIN 64
#define P_TOT 131072   // 8*16384
#define EPS 1e-5f

// ---------------------------------------------------------------- block reduce
__device__ __forceinline__ void blockReduce2(float& a, float& b2, float* lds) {
#pragma unroll
  for (int off = 32; off > 0; off >>= 1) {
    a  += __shfl_down(a,  off, 64);
    b2 += __shfl_down(b2, off, 64);
  }
  int wv = threadIdx.x >> 6, ln = threadIdx.x & 63;
  if (ln == 0) { lds[wv] = a; lds[4 + wv] = b2; }
  __syncthreads();
  if (threadIdx.x == 0) {
    a  = lds[0] + lds[1] + lds[2] + lds[3];
    b2 = lds[4] + lds[5] + lds[6] + lds[7];
  }
}

// ---------------------------------------------------------------- k0: transpose all weight matrices
// w_in [192][256] -> wTin[c][j]; w_qkv [576][192] -> wTqkv[c][j];
// w_proj [192][192] -> wTproj[c][o]; w_g [768][192] -> wTg[c][row]
__global__ __launch_bounds__(256) void k0_prep(
    const float* __restrict__ w_in, const float* __restrict__ w_qkv,
    const float* __restrict__ w_proj, const float* __restrict__ w_g,
    float* __restrict__ wTin, float* __restrict__ wTqkv,
    float* __restrict__ wTproj, float* __restrict__ wTg)
{
  int idx = blockIdx.x * 256 + threadIdx.x;   // < 344064
  if (idx < 49152) {
    int j = idx >> 8, c = idx & 255;
    wTin[c * 192 + j] = w_in[idx];
  } else if (idx < 159744) {
    int t = idx - 49152; int j = t / 192, c = t - j * 192;
    wTqkv[c * 576 + j] = w_qkv[t];
  } else if (idx < 196608) {
    int t = idx - 159744; int o = t / 192, c = t - o * 192;
    wTproj[c * 192 + o] = w_proj[t];
  } else if (idx < 344064) {
    int t = idx - 196608; int row = t / 192, c = t - row * 192;
    wTg[c * 768 + row] = w_g[t];
  }
}

// ---------------------------------------------------------------- k3: fused in_proj+LN+window attention
// one block per 4x4 window; weight loads lane-coalesced via transposed weights.
// LDS budget: 9216+3072+1088 floats = 53504 B  (<=54613 B keeps 3 blocks/CU)
__global__ __launch_bounds__(256) void k3_fused(
    const float* __restrict__ x,  const float* __restrict__ h,
    const float* __restrict__ wTin, const float* __restrict__ b_in,
    const float* __restrict__ ln_g, const float* __restrict__ ln_b,
    const float* __restrict__ wTqkv, const float* __restrict__ b_qkv,
    const float* __restrict__ wTproj, const float* __restrict__ b_proj,
    float* __restrict__ amap)
{
  __shared__ float buf[9216];   // comb[c][t] (stage A/B), then qkv[j][t] (stage E+)
  __shared__ float xnb[3072];   // in_proj out / normalized / attn-out
  __shared__ float scb[1088];   // LN partials + mu/rs, then scores [64][17] (padded)
  const int tid = threadIdx.x;
  const int wid = blockIdx.x;
  const int b  = wid >> 10;
  const int wy = (wid >> 5) & 31;
  const int wx = wid & 31;
  const int pix0 = (wy * 4) * W_IMG + wx * 4;

  // stage A: load x(64ch) + h(192ch) 4x4 tile into buf[c][t] (t = ty*4+tx)
  for (int idx = tid; idx < 1024; idx += 256) {
    int cch = idx >> 2, ty = idx & 3;
    const float* src = (cch < 64)
        ? x + (size_t)(b * CIN + cch) * HW + pix0 + ty * W_IMG
        : h + (size_t)(b * CH + (cch - 64)) * HW + pix0 + ty * W_IMG;
    const float4 v = *(const float4*)src;
    float* d = &buf[cch * 16 + ty * 4];
    d[0] = v.x; d[1] = v.y; d[2] = v.z; d[3] = v.w;
  }
  __syncthreads();

  // stage B: in_proj. 768 units = (j<192, q<4), 3 rounds, 100% util.
  // weight read wTin[c*192+j]: lanes j-consecutive -> coalesced.
  for (int r = 0; r < 3; ++r) {
    int idx = r * 256 + tid;
    int j = idx >> 2, q = idx & 3;
    float bj = b_in[j];
    float a0 = bj, a1 = bj, a2 = bj, a3 = bj;
    const float* xr = &buf[q * 4];
    const float* wp = wTin + j;
#pragma unroll 4
    for (int c = 0; c < 256; ++c) {
      float wv = wp[c * 192];
      const float* xc = xr + c * 16;
      a0 = fmaf(wv, xc[0], a0);
      a1 = fmaf(wv, xc[1], a1);
      a2 = fmaf(wv, xc[2], a2);
      a3 = fmaf(wv, xc[3], a3);
    }
    float* o = &xnb[j * 16 + q * 4];
    o[0] = a0; o[1] = a1; o[2] = a2; o[3] = a3;
  }
  __syncthreads();

  // stage C1: LN partial stats, all 256 threads: (g=tid>>4 over 12 ch, t=tid&15)
  {
    int g = tid >> 4, t = tid & 15;
    float s = 0.f, s2 = 0.f;
    const float* p = &xnb[g * 12 * 16 + t];
#pragma unroll
    for (int jj = 0; jj < 12; ++jj) { float v = p[jj * 16]; s += v; s2 = fmaf(v, v, s2); }
    scb[tid] = s; scb[256 + tid] = s2;
  }
  __syncthreads();
  // stage C2: finalize per-token stats
  if (tid < 16) {
    float s = 0.f, s2 = 0.f;
#pragma unroll
    for (int g = 0; g < 16; ++g) { s += scb[g * 16 + tid]; s2 += scb[256 + g * 16 + tid]; }
    float mu = s * (1.f / 192.f);
    float var = s2 * (1.f / 192.f) - mu * mu;
    scb[512 + tid] = mu;
    scb[528 + tid] = rsqrtf(fmaxf(var, 0.f) + EPS);
  }
  __syncthreads();

  // stage D: normalize in place
  for (int idx = tid; idx < 3072; idx += 256) {
    int j = idx >> 4, t = idx & 15;
    xnb[idx] = (xnb[idx] - scb[512 + t]) * scb[528 + t] * ln_g[j] + ln_b[j];
  }
  __syncthreads();

  // stage E: qkv GEMM. 2304 units = (j<576, q<4), 9 rounds, 100% util.
  for (int r = 0; r < 9; ++r) {
    int idx = r * 256 + tid;
    int j = idx >> 2, q = idx & 3;
    float bj = b_qkv[j];
    float a0 = bj, a1 = bj, a2 = bj, a3 = bj;
    const float* xr = &xnb[q * 4];
    const float* wp = wTqkv + j;
#pragma unroll 4
    for (int c = 0; c < 192; ++c) {
      float wv = wp[c * 576];
      const float* xc = xr + c * 16;
      a0 = fmaf(wv, xc[0], a0);
      a1 = fmaf(wv, xc[1], a1);
      a2 = fmaf(wv, xc[2], a2);
      a3 = fmaf(wv, xc[3], a3);
    }
    float* o = &buf[j * 16 + q * 4];
    o[0] = a0; o[1] = a1; o[2] = a2; o[3] = a3;
  }
  __syncthreads();

  // stage F: scores into padded rows scb[(hh*16+t1)*17 + t2]
  const float scale = 0.14433756729740643f;  // 48^-0.5
  for (int r = 0; r < 4; ++r) {
    int idx = r * 256 + tid;
    int hh = idx >> 8, t1 = (idx >> 4) & 15, t2 = idx & 15;
    const float* qq = &buf[(hh * 48) * 16 + t1];
    const float* kk = &buf[(192 + hh * 48) * 16 + t2];
    float sv = 0.f;
#pragma unroll
    for (int d = 0; d < 48; ++d) sv = fmaf(qq[d * 16], kk[d * 16], sv);
    scb[(hh * 16 + t1) * 17 + t2] = sv * scale;
  }
  __syncthreads();

  // stage G: softmax, 4 lanes per row (64 rows), shfl reduce within 4-lane group
  {
    int rrow = tid >> 2, i = tid & 3;
    float* row = &scb[rrow * 17 + i * 4];
    float v0 = row[0], v1 = row[1], v2 = row[2], v3 = row[3];
    float m = fmaxf(fmaxf(v0, v1), fmaxf(v2, v3));
    m = fmaxf(m, __shfl_xor(m, 1));
    m = fmaxf(m, __shfl_xor(m, 2));
    float e0 = __expf(v0 - m), e1 = __expf(v1 - m);
    float e2 = __expf(v2 - m), e3 = __expf(v3 - m);
    float s = e0 + e1 + e2 + e3;
    s += __shfl_xor(s, 1);
    s += __shfl_xor(s, 2);
    float inv = 1.f / s;
    row[0] = e0 * inv; row[1] = e1 * inv; row[2] = e2 * inv; row[3] = e3 * inv;
  }
  __syncthreads();

  // stage H: attn-out[c][t] = sum_t2 P[h(c)][t][t2]*v[t2][c]  (into xnb)
  for (int r = 0; r < 12; ++r) {
    int idx = r * 256 + tid;  // < 3072
    int cc = idx >> 4, t = idx & 15;
    const float* pr = &scb[((cc / 48) * 16 + t) * 17];
    const float* vr = &buf[(384 + cc) * 16];
    float sv = 0.f;
#pragma unroll
    for (int t2 = 0; t2 < 16; ++t2) sv = fmaf(pr[t2], vr[t2], sv);
    xnb[cc * 16 + t] = sv;
  }
  __syncthreads();

  // stage I: out proj -> amap (raw, pre-GN). 768 units = (o<192, q<4), 3 rounds.
  for (int r = 0; r < 3; ++r) {
    int idx = r * 256 + tid;
    int o = idx >> 2, q = idx & 3;
    float bo = b_proj[o];
    float a0 = bo, a1 = bo, a2 = bo, a3 = bo;
    const float* xr = &xnb[q * 4];
    const float* wp = wTproj + o;
#pragma unroll 4
    for (int c = 0; c < 192; ++c) {
      float wv = wp[c * 192];
      const float* xc = xr + c * 16;
      a0 = fmaf(wv, xc[0], a0);
      a1 = fmaf(wv, xc[1], a1);
      a2 = fmaf(wv, xc[2], a2);
      a3 = fmaf(wv, xc[3], a3);
    }
    float* op = amap + (size_t)(b * CH + o) * HW + pix0 + q * W_IMG;
    *(float4*)op = make_float4(a0, a1, a2, a3);
  }
}

// ---------------------------------------------------------------- k4: GN stats (sum, sum2) per (b, group)
__global__ __launch_bounds__(256) void k4_stats(
    const float* __restrict__ src, float* __restrict__ stats)
{
  __shared__ float lds[8];
  int blk = blockIdx.x;             // 24576 = 1536 bc * 16 chunks
  int chunk = blk & 15, bc = blk >> 4;
  int b = bc / 192, cch = bc % 192;
  const float4 v = *(const float4*)(src + (size_t)bc * HW + chunk * 1024 + threadIdx.x * 4);
  float s  = v.x + v.y + v.z + v.w;
  float s2 = v.x * v.x + v.y * v.y + v.z * v.z + v.w * v.w;
  blockReduce2(s, s2, lds);
  if (threadIdx.x == 0) {
    atomicAdd(&stats[(b * 8 + cch / 24) * 2],     s);
    atomicAdd(&stats[(b * 8 + cch / 24) * 2 + 1], s2);
  }
}

// ---------------------------------------------------------------- k4b: per-(b,c) GN scale/shift for amap
__global__ __launch_bounds__(256) void k4b_scale(
    const float* __restrict__ stats, const float* __restrict__ gn_g,
    const float* __restrict__ gn_b, float* __restrict__ scaleS, float* __restrict__ shiftS)
{
  int idx = blockIdx.x * 256 + threadIdx.x;
  if (idx >= 1536) return;
  int b = idx / 192, cch = idx % 192, g = cch / 24;
  float n = 24.f * HW;
  float mu  = stats[(b * 8 + g) * 2] / n;
  float var = stats[(b * 8 + g) * 2 + 1] / n - mu * mu;
  float rs = rsqrtf(fmaxf(var, 0.f) + EPS);
  float scl = rs * gn_g[cch];
  scaleS[idx] = scl;
  shiftS[idx] = gn_b[cch] - mu * scl;
}

// ---------------------------------------------------------------- k6: gates GEMM (+folded GN) + LSTM
__global__ __launch_bounds__(256) void k6_gates(
    float* __restrict__ outp,            // hnext region == amap (in), hnext-pre (out)
    const float* __restrict__ wT,        // [c][row] 192x768
    const float* __restrict__ b_g, const float* __restrict__ cin,
    const float* __restrict__ scaleS, const float* __restrict__ shiftS)
{
  __shared__ float tile[192 * 64];   // 48 KB, [c][p] normalized amap
  const int tid = threadIdx.x;
  const int b  = blockIdx.x >> 8;            // 2048 blocks = 8 b x 256
  const int s0 = (blockIdx.x & 255) * 64;
  float* cout = outp + (size_t)P_TOT * CH;

  for (int idx = tid; idx < 12288; idx += 256) {
    int c = idx >> 6, p = idx & 63;
    float raw = outp[(size_t)(b * CH + c) * HW + s0 + p];
    tile[idx] = fmaf(raw, scaleS[b * CH + c], shiftS[b * CH + c]);
  }
  __syncthreads();

  const int lane = tid & 63;
  const int wv = __builtin_amdgcn_readfirstlane(tid >> 6);

  for (int jg = wv * 6; jg < wv * 6 + 6; ++jg) {
    const int j0 = jg * 8;
    float acc[32];
#pragma unroll
    for (int k = 0; k < 4; ++k)
#pragma unroll
      for (int r = 0; r < 8; ++r) acc[k * 8 + r] = b_g[k * 192 + j0 + r];
#pragma unroll 2
    for (int c = 0; c < 192; ++c) {
      float a = tile[c * 64 + lane];
      const float* wc = wT + (size_t)c * 768 + j0;
#pragma unroll
      for (int k = 0; k < 4; ++k)
#pragma unroll
        for (int r = 0; r < 8; ++r)
          acc[k * 8 + r] = fmaf(a, wc[k * 192 + r], acc[k * 8 + r]);
    }
#pragma unroll
    for (int r = 0; r < 8; ++r) {
      size_t base = (size_t)(b * CH + j0 + r) * HW + s0 + lane;
      float ci = acc[r], cf = acc[8 + r], co = acc[16 + r], cg = acc[24 + r];
      float iv = 1.f / (1.f + __expf(-ci));
      float fv = 1.f / (1.f + __expf(-cf));
      float ov = 1.f / (1.f + __expf(-co));
      float gv = 1.f - 2.f / (__expf(2.f * cg) + 1.f);
      float cn = fmaf(fv, cin[base], iv * gv);
      cout[base] = cn;                                   // cnext (final)
      float th = 1.f - 2.f / (__expf(2.f * cn) + 1.f);
      outp[base] = ov * th;                              // hnext pre-GN
    }
  }
}

// ---------------------------------------------------------------- k7: GN(hnext) in place
__global__ __launch_bounds__(256) void k7_hnext(
    const float* __restrict__ stats2,
    const float* __restrict__ gn_g, const float* __restrict__ gn_b,
    float* __restrict__ outp)
{
  int blk = blockIdx.x;
  int chunk = blk & 15, bc = blk >> 4;
  int b = bc / 192, cch = bc % 192, g = cch / 24;
  float n = 24.f * HW;
  float mu  = stats2[(b * 8 + g) * 2] / n;
  float var = stats2[(b * 8 + g) * 2 + 1] / n - mu * mu;
  float rs = rsqrtf(fmaxf(var, 0.f) + EPS);
  float scl = rs * gn_g[cch];
  float shf = gn_b[cch] - mu * scl;
  float* p = outp + (size_t)bc * HW + chunk * 1024 + threadIdx.x * 4;
  float4 v = *(float4*)p;
  v.x = fmaf(v.x, scl, shf); v.y = fmaf(v.y, scl, shf);
  v.z = fmaf(v.z, scl, shf); v.w = fmaf(v.w, scl, shf);
  *(float4*)p = v;
}

// ---------------------------------------------------------------- launch
extern "C" void kernel_launch(void* const* d_in, const int* in_sizes, int n_in,
                              void* d_out, int out_size, void* d_ws, size_t ws_size,
                              hipStream_t stream) {
  (void)in_sizes; (void)n_in; (void)out_size; (void)ws_size;
  const float* x      = (const float*)d_in[0];
  const float* h      = (const float*)d_in[1];
  const float* c      = (const float*)d_in[2];
  const float* w_in   = (const float*)d_in[3];
  const float* b_in   = (const float*)d_in[4];
  const float* ln_g   = (const float*)d_in[5];
  const float* ln_b   = (const float*)d_in[6];
  const float* w_qkv  = (const float*)d_in[7];
  const float* b_qkv  = (const float*)d_in[8];
  const float* w_proj = (const float*)d_in[9];
  const float* b_proj = (const float*)d_in[10];
  const float* gn_g   = (const float*)d_in[11];
  const float* gn_b   = (const float*)d_in[12];
  const float* w_g    = (const float*)d_in[13];
  const float* b_g    = (const float*)d_in[14];
  float* outp = (float*)d_out;
  char* ws = (char*)d_ws;
  // workspace layout: 1,389,568 B total
  float* wTin   = (float*)ws;                    // 196,608 B
  float* wTqkv  = (float*)(ws + 196608);         // 442,368 B
  float* wTproj = (float*)(ws + 638976);         // 147,456 B
  float* wTg    = (float*)(ws + 786432);         // 589,824 B
  float* statsA = (float*)(ws + 1376256);        // 512 B
  float* stats2 = (float*)(ws + 1376768);        // 512 B
  float* scaleS = (float*)(ws + 1377280);        // 6,144 B
  float* shiftS = (float*)(ws + 1383424);        // 6,144 B

  hipMemsetAsync(statsA, 0, 1024, stream);       // statsA + stats2

  k0_prep  <<<1344, 256, 0, stream>>>(w_in, w_qkv, w_proj, w_g,
                                      wTin, wTqkv, wTproj, wTg);
  k3_fused <<<8192, 256, 0, stream>>>(x, h, wTin, b_in, ln_g, ln_b,
                                      wTqkv, b_qkv, wTproj, b_proj, outp);
  k4_stats <<<24576, 256, 0, stream>>>(outp, statsA);
  k4b_scale<<<6, 256, 0, stream>>>(statsA, gn_g, gn_b, scaleS, shiftS);
  k6_gates <<<2048, 256, 0, stream>>>(outp, wTg, b_g, c, scaleS, shiftS);
  k4_stats <<<24576, 256, 0, stream>>>(outp, stats2);
  k7_hnext <<<24576, 256, 0, stream>>>(stats2, gn_g, gn_b, outp);
}

// Round 3
// 3204.755 us; speedup vs baseline: 1.3091x; 1.3091x over previous
//
#include <hip/hip_runtime.h>

#define HW 16384
#define W_IMG 128
#define CH 192
#define CIN 64
#define P_TOT 131072   // 8*16384
#define EPS 1e-5f

// ---------------------------------------------------------------- block reduce
__device__ __forceinline__ void blockReduce2(float& a, float& b2, float* lds) {
#pragma unroll
  for (int off = 32; off > 0; off >>= 1) {
    a  += __shfl_down(a,  off, 64);
    b2 += __shfl_down(b2, off, 64);
  }
  int wv = threadIdx.x >> 6, ln = threadIdx.x & 63;
  if (ln == 0) { lds[wv] = a; lds[4 + wv] = b2; }
  __syncthreads();
  if (threadIdx.x == 0) {
    a  = lds[0] + lds[1] + lds[2] + lds[3];
    b2 = lds[4] + lds[5] + lds[6] + lds[7];
  }
}

// ---------------------------------------------------------------- k0: transpose w_gates -> wT[c][row]
__global__ __launch_bounds__(256) void k0_prep(
    const float* __restrict__ w_g, float* __restrict__ wT)
{
  int idx = blockIdx.x * 256 + threadIdx.x;   // < 147456
  if (idx < 147456) {
    int row = idx / 192, c = idx - row * 192;
    wT[(size_t)c * 768 + row] = w_g[idx];
  }
}

// ---------------------------------------------------------------- k3: fused in_proj+LN+window attention
// one block per 4x4 window. Row-streaming weights (L1-friendly).
// LDS: qk 6144 + xnb 3072 + scr 544 = 9760 floats = 38.1 KB -> 4 blocks/CU.
__global__ __launch_bounds__(256) void k3_fused(
    const float* __restrict__ x,  const float* __restrict__ h,
    const float* __restrict__ w_in, const float* __restrict__ b_in,
    const float* __restrict__ ln_g, const float* __restrict__ ln_b,
    const float* __restrict__ w_qkv, const float* __restrict__ b_qkv,
    const float* __restrict__ w_proj, const float* __restrict__ b_proj,
    float* __restrict__ amap)
{
  __shared__ float qk[6144];   // A/B: comb[c][t] (4096). E: q rows [0:3072], k rows [3072:6144].
                               // After F1/F2: P (stride 17) in [0:1088]. After F2: v in [3072:6144].
  __shared__ float xnb[3072];  // xn (B..V), then attn-out (H..I)
  __shared__ float scr[544];   // LN partials (512) + mu(16)+rs(16); later per-pair scores 32x17
  const int tid = threadIdx.x;
  const int wid = blockIdx.x;
  const int b  = wid >> 10;
  const int wy = (wid >> 5) & 31;
  const int wx = wid & 31;
  const int pix0 = (wy * 4) * W_IMG + wx * 4;

  // stage A: load x(64ch) + h(192ch) 4x4 tile into qk[c][t] (comb), t = ty*4+tx
  for (int idx = tid; idx < 1024; idx += 256) {
    int cch = idx >> 2, ty = idx & 3;
    const float* src = (cch < 64)
        ? x + (size_t)(b * CIN + cch) * HW + pix0 + ty * W_IMG
        : h + (size_t)(b * CH + (cch - 64)) * HW + pix0 + ty * W_IMG;
    const float4 v = *(const float4*)src;
    float* d = &qk[cch * 16 + ty * 4];
    d[0] = v.x; d[1] = v.y; d[2] = v.z; d[3] = v.w;
  }
  __syncthreads();

  // stage B: in_proj. thread j<192 streams w_in row j (L1 line reuse), acc[16].
  if (tid < 192) {
    const int j = tid;
    float acc[16];
    float bj = b_in[j];
#pragma unroll
    for (int t = 0; t < 16; ++t) acc[t] = bj;
    const float* wr = w_in + (size_t)j * 256;
#pragma unroll 4
    for (int c = 0; c < 256; ++c) {
      float wv = wr[c];
      const float* xr = &qk[c * 16];
#pragma unroll
      for (int t = 0; t < 16; ++t) acc[t] = fmaf(wv, xr[t], acc[t]);
    }
    float* o = &xnb[j * 16];
#pragma unroll
    for (int t = 0; t < 16; ++t) o[t] = acc[t];
  }
  __syncthreads();

  // stage C1: LN partial stats, all 256 threads (g=tid>>4 over 12 ch, t=tid&15)
  {
    int g = tid >> 4, t = tid & 15;
    float s = 0.f, s2 = 0.f;
    const float* p = &xnb[g * 12 * 16 + t];
#pragma unroll
    for (int jj = 0; jj < 12; ++jj) { float v = p[jj * 16]; s += v; s2 = fmaf(v, v, s2); }
    scr[tid] = s; scr[256 + tid] = s2;
  }
  __syncthreads();
  // stage C2: finalize per-token stats
  if (tid < 16) {
    float s = 0.f, s2 = 0.f;
#pragma unroll
    for (int g = 0; g < 16; ++g) { s += scr[g * 16 + tid]; s2 += scr[256 + g * 16 + tid]; }
    float mu = s * (1.f / 192.f);
    float var = s2 * (1.f / 192.f) - mu * mu;
    scr[512 + tid] = mu;
    scr[528 + tid] = rsqrtf(fmaxf(var, 0.f) + EPS);
  }
  __syncthreads();

  // stage D: normalize in place
  for (int idx = tid; idx < 3072; idx += 256) {
    int j = idx >> 4, t = idx & 15;
    xnb[idx] = (xnb[idx] - scr[512 + t]) * scr[528 + t] * ln_g[j] + ln_b[j];
  }
  __syncthreads();

  // stage E: q,k GEMM only (rows 0..383 of w_qkv). units (j<384, token-half),
  // 768 units = 3 full rounds, 100% util, acc[8], row-streaming weights.
  for (int r = 0; r < 3; ++r) {
    int idx = r * 256 + tid;
    int j = idx >> 1, th = idx & 1;      // j < 384
    float bj = b_qkv[j];
    float acc[8];
#pragma unroll
    for (int i = 0; i < 8; ++i) acc[i] = bj;
    const float* wr = w_qkv + (size_t)j * 192;
    const float* xr = &xnb[th * 8];
#pragma unroll 4
    for (int c = 0; c < 192; ++c) {
      float wv = wr[c];
      const float* xc = xr + c * 16;
#pragma unroll
      for (int i = 0; i < 8; ++i) acc[i] = fmaf(wv, xc[i], acc[i]);
    }
    float* o = &qk[j * 16 + th * 8];     // q rows at [0:3072], k rows at [3072:6144]
#pragma unroll
    for (int i = 0; i < 8; ++i) o[i] = acc[i];
  }
  __syncthreads();

  // stages F/G per head-pair p in {0,1}: scores -> scr (32x17), softmax,
  // normalized P -> qk[(p*32+row)*17 + t2] (dead q-head01 region, max idx 1086 < 1536)
  const float scale = 0.14433756729740643f;  // 48^-0.5
#pragma unroll
  for (int p = 0; p < 2; ++p) {
    // F: 512 units (hhl<2, t1<16, t2<16) = 2 full rounds
    for (int r = 0; r < 2; ++r) {
      int idx = r * 256 + tid;
      int hhl = idx >> 8, t1 = (idx >> 4) & 15, t2 = idx & 15;
      int hh = 2 * p + hhl;
      const float* qq = &qk[(hh * 48) * 16 + t1];
      const float* kk = &qk[3072 + (hh * 48) * 16 + t2];
      float sv = 0.f;
#pragma unroll
      for (int d = 0; d < 48; ++d) sv = fmaf(qq[d * 16], kk[d * 16], sv);
      scr[(hhl * 16 + t1) * 17 + t2] = sv * scale;
    }
    __syncthreads();
    // G: softmax, 4 lanes per row, 32 rows (128 threads)
    if (tid < 128) {
      int rrow = tid >> 2, i = tid & 3;
      const float* row = &scr[rrow * 17 + i * 4];
      float v0 = row[0], v1 = row[1], v2 = row[2], v3 = row[3];
      float m = fmaxf(fmaxf(v0, v1), fmaxf(v2, v3));
      m = fmaxf(m, __shfl_xor(m, 1));
      m = fmaxf(m, __shfl_xor(m, 2));
      float e0 = __expf(v0 - m), e1 = __expf(v1 - m);
      float e2 = __expf(v2 - m), e3 = __expf(v3 - m);
      float s = e0 + e1 + e2 + e3;
      s += __shfl_xor(s, 1);
      s += __shfl_xor(s, 2);
      float inv = 1.f / s;
      float* pd = &qk[(p * 32 + rrow) * 17 + i * 4];
      pd[0] = e0 * inv; pd[1] = e1 * inv; pd[2] = e2 * inv; pd[3] = e3 * inv;
    }
    __syncthreads();
  }

  // stage V: v GEMM (rows 384..575 of w_qkv) into dead k region qk[3072:6144].
  // thread j<192 streams its row, acc[16]. Reads xnb (xn) - still live.
  if (tid < 192) {
    const int j = tid;
    float acc[16];
    float bj = b_qkv[384 + j];
#pragma unroll
    for (int t = 0; t < 16; ++t) acc[t] = bj;
    const float* wr = w_qkv + (size_t)(384 + j) * 192;
#pragma unroll 4
    for (int c = 0; c < 192; ++c) {
      float wv = wr[c];
      const float* xr = &xnb[c * 16];
#pragma unroll
      for (int t = 0; t < 16; ++t) acc[t] = fmaf(wv, xr[t], acc[t]);
    }
    float* o = &qk[3072 + j * 16];
#pragma unroll
    for (int t = 0; t < 16; ++t) o[t] = acc[t];
  }
  __syncthreads();

  // stage H: attn-out[c][t] = sum_t2 P[h(c)][t][t2] * v[c][t2]  -> xnb (xn dead)
  for (int r = 0; r < 12; ++r) {
    int idx = r * 256 + tid;  // < 3072
    int cc = idx >> 4, t = idx & 15;
    const float* pr = &qk[((cc / 48) * 16 + t) * 17];
    const float* vr = &qk[3072 + cc * 16];
    float sv = 0.f;
#pragma unroll
    for (int t2 = 0; t2 < 16; ++t2) sv = fmaf(pr[t2], vr[t2], sv);
    xnb[cc * 16 + t] = sv;
  }
  __syncthreads();

  // stage I: out proj -> amap (raw, pre-GN). thread o<192 streams w_proj row o.
  if (tid < 192) {
    const int o = tid;
    float acc[16];
    float bo = b_proj[o];
#pragma unroll
    for (int t = 0; t < 16; ++t) acc[t] = bo;
    const float* wr = w_proj + (size_t)o * 192;
#pragma unroll 4
    for (int c = 0; c < 192; ++c) {
      float wv = wr[c];
      const float* xr = &xnb[c * 16];
#pragma unroll
      for (int t = 0; t < 16; ++t) acc[t] = fmaf(wv, xr[t], acc[t]);
    }
    float* op = amap + (size_t)(b * CH + o) * HW + pix0;
#pragma unroll
    for (int ty = 0; ty < 4; ++ty) {
      *(float4*)(op + ty * W_IMG) =
          make_float4(acc[ty * 4], acc[ty * 4 + 1], acc[ty * 4 + 2], acc[ty * 4 + 3]);
    }
  }
}

// ---------------------------------------------------------------- k4: GN stats (sum, sum2) per (b, group)
__global__ __launch_bounds__(256) void k4_stats(
    const float* __restrict__ src, float* __restrict__ stats)
{
  __shared__ float lds[8];
  int blk = blockIdx.x;             // 24576 = 1536 bc * 16 chunks
  int chunk = blk & 15, bc = blk >> 4;
  int b = bc / 192, cch = bc % 192;
  const float4 v = *(const float4*)(src + (size_t)bc * HW + chunk * 1024 + threadIdx.x * 4);
  float s  = v.x + v.y + v.z + v.w;
  float s2 = v.x * v.x + v.y * v.y + v.z * v.z + v.w * v.w;
  blockReduce2(s, s2, lds);
  if (threadIdx.x == 0) {
    atomicAdd(&stats[(b * 8 + cch / 24) * 2],     s);
    atomicAdd(&stats[(b * 8 + cch / 24) * 2 + 1], s2);
  }
}

// ---------------------------------------------------------------- k4b: per-(b,c) GN scale/shift for amap
__global__ __launch_bounds__(256) void k4b_scale(
    const float* __restrict__ stats, const float* __restrict__ gn_g,
    const float* __restrict__ gn_b, float* __restrict__ scaleS, float* __restrict__ shiftS)
{
  int idx = blockIdx.x * 256 + threadIdx.x;
  if (idx >= 1536) return;
  int b = idx / 192, cch = idx % 192, g = cch / 24;
  float n = 24.f * HW;
  float mu  = stats[(b * 8 + g) * 2] / n;
  float var = stats[(b * 8 + g) * 2 + 1] / n - mu * mu;
  float rs = rsqrtf(fmaxf(var, 0.f) + EPS);
  float scl = rs * gn_g[cch];
  scaleS[idx] = scl;
  shiftS[idx] = gn_b[cch] - mu * scl;
}

// ---------------------------------------------------------------- k6: gates GEMM (+folded GN) + LSTM
__global__ __launch_bounds__(256) void k6_gates(
    float* __restrict__ outp,            // hnext region == amap (in), hnext-pre (out)
    const float* __restrict__ wT,        // [c][row] 192x768
    const float* __restrict__ b_g, const float* __restrict__ cin,
    const float* __restrict__ scaleS, const float* __restrict__ shiftS)
{
  __shared__ float tile[192 * 64];   // 48 KB, [c][p] normalized amap
  const int tid = threadIdx.x;
  const int b  = blockIdx.x >> 8;            // 2048 blocks = 8 b x 256
  const int s0 = (blockIdx.x & 255) * 64;
  float* cout = outp + (size_t)P_TOT * CH;

  for (int idx = tid; idx < 12288; idx += 256) {
    int c = idx >> 6, p = idx & 63;
    float raw = outp[(size_t)(b * CH + c) * HW + s0 + p];
    tile[idx] = fmaf(raw, scaleS[b * CH + c], shiftS[b * CH + c]);
  }
  __syncthreads();

  const int lane = tid & 63;
  const int wv = __builtin_amdgcn_readfirstlane(tid >> 6);

  for (int jg = wv * 6; jg < wv * 6 + 6; ++jg) {
    const int j0 = jg * 8;
    float acc[32];
#pragma unroll
    for (int k = 0; k < 4; ++k)
#pragma unroll
      for (int r = 0; r < 8; ++r) acc[k * 8 + r] = b_g[k * 192 + j0 + r];
#pragma unroll 2
    for (int c = 0; c < 192; ++c) {
      float a = tile[c * 64 + lane];
      const float* wc = wT + (size_t)c * 768 + j0;
#pragma unroll
      for (int k = 0; k < 4; ++k)
#pragma unroll
        for (int r = 0; r < 8; ++r)
          acc[k * 8 + r] = fmaf(a, wc[k * 192 + r], acc[k * 8 + r]);
    }
#pragma unroll
    for (int r = 0; r < 8; ++r) {
      size_t base = (size_t)(b * CH + j0 + r) * HW + s0 + lane;
      float ci = acc[r], cf = acc[8 + r], co = acc[16 + r], cg = acc[24 + r];
      float iv = 1.f / (1.f + __expf(-ci));
      float fv = 1.f / (1.f + __expf(-cf));
      float ov = 1.f / (1.f + __expf(-co));
      float gv = 1.f - 2.f / (__expf(2.f * cg) + 1.f);
      float cn = fmaf(fv, cin[base], iv * gv);
      cout[base] = cn;                                   // cnext (final)
      float th = 1.f - 2.f / (__expf(2.f * cn) + 1.f);
      outp[base] = ov * th;                              // hnext pre-GN
    }
  }
}

// ---------------------------------------------------------------- k7: GN(hnext) in place
__global__ __launch_bounds__(256) void k7_hnext(
    const float* __restrict__ stats2,
    const float* __restrict__ gn_g, const float* __restrict__ gn_b,
    float* __restrict__ outp)
{
  int blk = blockIdx.x;
  int chunk = blk & 15, bc = blk >> 4;
  int b = bc / 192, cch = bc % 192, g = cch / 24;
  float n = 24.f * HW;
  float mu  = stats2[(b * 8 + g) * 2] / n;
  float var = stats2[(b * 8 + g) * 2 + 1] / n - mu * mu;
  float rs = rsqrtf(fmaxf(var, 0.f) + EPS);
  float scl = rs * gn_g[cch];
  float shf = gn_b[cch] - mu * scl;
  float* p = outp + (size_t)bc * HW + chunk * 1024 + threadIdx.x * 4;
  float4 v = *(float4*)p;
  v.x = fmaf(v.x, scl, shf); v.y = fmaf(v.y, scl, shf);
  v.z = fmaf(v.z, scl, shf); v.w = fmaf(v.w, scl, shf);
  *(float4*)p = v;
}

// ---------------------------------------------------------------- launch
extern "C" void kernel_launch(void* const* d_in, const int* in_sizes, int n_in,
                              void* d_out, int out_size, void* d_ws, size_t ws_size,
                              hipStream_t stream) {
  (void)in_sizes; (void)n_in; (void)out_size; (void)ws_size;
  const float* x      = (const float*)d_in[0];
  const float* h      = (const float*)d_in[1];
  const float* c      = (const float*)d_in[2];
  const float* w_in   = (const float*)d_in[3];
  const float* b_in   = (const float*)d_in[4];
  const float* ln_g   = (const float*)d_in[5];
  const float* ln_b   = (const float*)d_in[6];
  const float* w_qkv  = (const float*)d_in[7];
  const float* b_qkv  = (const float*)d_in[8];
  const float* w_proj = (const float*)d_in[9];
  const float* b_proj = (const float*)d_in[10];
  const float* gn_g   = (const float*)d_in[11];
  const float* gn_b   = (const float*)d_in[12];
  const float* w_g    = (const float*)d_in[13];
  const float* b_g    = (const float*)d_in[14];
  float* outp = (float*)d_out;
  char* ws = (char*)d_ws;
  // workspace: 603,136 B total
  float* wT     = (float*)ws;                   // 589,824 B
  float* statsA = (float*)(ws + 589824);        // 512 B
  float* stats2 = (float*)(ws + 590336);        // 512 B
  float* scaleS = (float*)(ws + 590848);        // 6,144 B
  float* shiftS = (float*)(ws + 596992);        // 6,144 B

  hipMemsetAsync(statsA, 0, 1024, stream);      // statsA + stats2

  k0_prep  <<<576, 256, 0, stream>>>(w_g, wT);
  k3_fused <<<8192, 256, 0, stream>>>(x, h, w_in, b_in, ln_g, ln_b,
                                      w_qkv, b_qkv, w_proj, b_proj, outp);
  k4_stats <<<24576, 256, 0, stream>>>(outp, statsA);
  k4b_scale<<<6, 256, 0, stream>>>(statsA, gn_g, gn_b, scaleS, shiftS);
  k6_gates <<<2048, 256, 0, stream>>>(outp, wT, b_g, c, scaleS, shiftS);
  k4_stats <<<24576, 256, 0, stream>>>(outp, stats2);
  k7_hnext <<<24576, 256, 0, stream>>>(stats2, gn_g, gn_b, outp);
}

// Round 4
// 2998.098 us; speedup vs baseline: 1.3993x; 1.0689x over previous
//
#include <hip/hip_runtime.h>

#define HW 16384
#define W_IMG 128
#define CH 192
#define CIN 64
#define P_TOT 131072   // 8*16384
#define EPS 1e-5f

// ---------------------------------------------------------------- block reduce
__device__ __forceinline__ void blockReduce2(float& a, float& b2, float* lds) {
#pragma unroll
  for (int off = 32; off > 0; off >>= 1) {
    a  += __shfl_down(a,  off, 64);
    b2 += __shfl_down(b2, off, 64);
  }
  int wv = threadIdx.x >> 6, ln = threadIdx.x & 63;
  if (ln == 0) { lds[wv] = a; lds[4 + wv] = b2; }
  __syncthreads();
  if (threadIdx.x == 0) {
    a  = lds[0] + lds[1] + lds[2] + lds[3];
    b2 = lds[4] + lds[5] + lds[6] + lds[7];
  }
}

// ---------------------------------------------------------------- k0: transpose w_gates -> wT[c][row]
__global__ __launch_bounds__(256) void k0_prep(
    const float* __restrict__ w_g, float* __restrict__ wT)
{
  int idx = blockIdx.x * 256 + threadIdx.x;   // < 147456
  if (idx < 147456) {
    int row = idx / 192, c = idx - row * 192;
    wT[(size_t)c * 768 + row] = w_g[idx];
  }
}

// ---------------------------------------------------------------- register-tiled 3-row GEMM helper
// thread = (ju = tid>>2, kp = tid&3). Rows j0..j0+2; K-slice c = 4*cc + kp.
// acc[3][16] in regs; 48 FMA per 4 ds_read_b128 (broadcast). shfl_xor(1,2)
// reduces over kp (lane bits 0-1); each kp lane writes its token-quarter.
__device__ __forceinline__ float4 pick4(const float s[16], int kp, float bj) {
  if (kp == 0) return make_float4(s[0] + bj, s[1] + bj, s[2] + bj, s[3] + bj);
  if (kp == 1) return make_float4(s[4] + bj, s[5] + bj, s[6] + bj, s[7] + bj);
  if (kp == 2) return make_float4(s[8] + bj, s[9] + bj, s[10] + bj, s[11] + bj);
  return make_float4(s[12] + bj, s[13] + bj, s[14] + bj, s[15] + bj);
}

template<int KCC>   // KCC = K/4 iterations
__device__ __forceinline__ void gemm3(
    const float* __restrict__ w0, int wld,        // weight row j0, leading dim
    const float* __restrict__ bias,               // &bias[j0]
    const float* __restrict__ xin,                // LDS [c][16]
    float* __restrict__ outBase,                  // row j0 base (LDS or global)
    int rs, int ks,                               // row stride, kp stride (floats)
    int kp)
{
  float acc[3][16];
#pragma unroll
  for (int r = 0; r < 3; ++r)
#pragma unroll
    for (int t = 0; t < 16; ++t) acc[r][t] = 0.f;

  const float* wp0 = w0 + kp;
  const float* wp1 = w0 + wld + kp;
  const float* wp2 = w0 + 2 * wld + kp;

#pragma unroll 2
  for (int cc = 0; cc < KCC; ++cc) {
    float wa = wp0[cc * 4];
    float wb = wp1[cc * 4];
    float wc = wp2[cc * 4];
    const float4* xc = (const float4*)&xin[(cc * 4 + kp) << 4];
    float4 x0 = xc[0], x1 = xc[1], x2 = xc[2], x3 = xc[3];
    float xv[16] = {x0.x, x0.y, x0.z, x0.w, x1.x, x1.y, x1.z, x1.w,
                    x2.x, x2.y, x2.z, x2.w, x3.x, x3.y, x3.z, x3.w};
#pragma unroll
    for (int t = 0; t < 16; ++t) {
      acc[0][t] = fmaf(wa, xv[t], acc[0][t]);
      acc[1][t] = fmaf(wb, xv[t], acc[1][t]);
      acc[2][t] = fmaf(wc, xv[t], acc[2][t]);
    }
  }

#pragma unroll
  for (int r = 0; r < 3; ++r) {
#pragma unroll
    for (int t = 0; t < 16; ++t) {
      float v = acc[r][t];
      v += __shfl_xor(v, 1);
      v += __shfl_xor(v, 2);
      acc[r][t] = v;
    }
    float4 o = pick4(acc[r], kp, bias[r]);
    *(float4*)&outBase[r * rs + kp * ks] = o;
  }
}

// ---------------------------------------------------------------- k3: fused in_proj+LN+window attention
// one block per 4x4 window. GEMM stages register-tiled (3 rows x 16 tok, split-K4).
// LDS: qk 6144 + xnb 3072 + scr 544 = 9760 floats = 38.1 KB -> 4 blocks/CU.
__global__ __launch_bounds__(256, 4) void k3_fused(
    const float* __restrict__ x,  const float* __restrict__ h,
    const float* __restrict__ w_in, const float* __restrict__ b_in,
    const float* __restrict__ ln_g, const float* __restrict__ ln_b,
    const float* __restrict__ w_qkv, const float* __restrict__ b_qkv,
    const float* __restrict__ w_proj, const float* __restrict__ b_proj,
    float* __restrict__ amap)
{
  __shared__ float qk[6144];   // A/B: comb[c][t]. E: q [0:3072], k [3072:6144].
                               // G writes P (stride 17) into [0:1088]; V -> [3072:6144].
  __shared__ float xnb[3072];  // in_proj out / xn, then attn-out
  __shared__ float scr[544];   // LN partials + mu/rs; later per-pair scores 32x17
  const int tid = threadIdx.x;
  const int ju  = tid >> 2;    // 64 row-units
  const int kp  = tid & 3;     // 4-way K split (lane bits 0-1)
  const int wid = blockIdx.x;
  const int b  = wid >> 10;
  const int wy = (wid >> 5) & 31;
  const int wx = wid & 31;
  const int pix0 = (wy * 4) * W_IMG + wx * 4;

  // stage A: load x(64ch) + h(192ch) 4x4 tile into qk[c][t] (comb), t = ty*4+tx
  for (int idx = tid; idx < 1024; idx += 256) {
    int cch = idx >> 2, ty = idx & 3;
    const float* src = (cch < 64)
        ? x + (size_t)(b * CIN + cch) * HW + pix0 + ty * W_IMG
        : h + (size_t)(b * CH + (cch - 64)) * HW + pix0 + ty * W_IMG;
    const float4 v = *(const float4*)src;
    float* d = &qk[cch * 16 + ty * 4];
    d[0] = v.x; d[1] = v.y; d[2] = v.z; d[3] = v.w;
  }
  __syncthreads();

  // stage B: in_proj (192 rows, K=256) -> xnb
  gemm3<64>(w_in + (size_t)(3 * ju) * 256, 256, b_in + 3 * ju,
            qk, &xnb[(3 * ju) * 16], 16, 4, kp);
  __syncthreads();

  // stage C1: LN partial stats, all 256 threads (g=tid>>4 over 12 ch, t=tid&15)
  {
    int g = tid >> 4, t = tid & 15;
    float s = 0.f, s2 = 0.f;
    const float* p = &xnb[g * 12 * 16 + t];
#pragma unroll
    for (int jj = 0; jj < 12; ++jj) { float v = p[jj * 16]; s += v; s2 = fmaf(v, v, s2); }
    scr[tid] = s; scr[256 + tid] = s2;
  }
  __syncthreads();
  // stage C2: finalize per-token stats
  if (tid < 16) {
    float s = 0.f, s2 = 0.f;
#pragma unroll
    for (int g = 0; g < 16; ++g) { s += scr[g * 16 + tid]; s2 += scr[256 + g * 16 + tid]; }
    float mu = s * (1.f / 192.f);
    float var = s2 * (1.f / 192.f) - mu * mu;
    scr[512 + tid] = mu;
    scr[528 + tid] = rsqrtf(fmaxf(var, 0.f) + EPS);
  }
  __syncthreads();

  // stage D: normalize in place
  for (int idx = tid; idx < 3072; idx += 256) {
    int j = idx >> 4, t = idx & 15;
    xnb[idx] = (xnb[idx] - scr[512 + t]) * scr[528 + t] * ln_g[j] + ln_b[j];
  }
  __syncthreads();

  // stage E: q,k GEMM (rows 0..383 of w_qkv, K=192) -> qk[j*16]
#pragma unroll
  for (int jp = 0; jp < 2; ++jp) {
    int j0 = jp * 192 + 3 * ju;
    gemm3<48>(w_qkv + (size_t)j0 * 192, 192, b_qkv + j0,
              xnb, &qk[j0 * 16], 16, 4, kp);
  }
  __syncthreads();

  // stages F/G per head-pair p: scores -> scr (32x17), softmax,
  // normalized P -> qk[(p*32+row)*17 + t2] (dead q-head01 region, max idx 1086)
  const float scale = 0.14433756729740643f;  // 48^-0.5
#pragma unroll
  for (int p = 0; p < 2; ++p) {
    for (int r = 0; r < 2; ++r) {
      int idx = r * 256 + tid;
      int hhl = idx >> 8, t1 = (idx >> 4) & 15, t2 = idx & 15;
      int hh = 2 * p + hhl;
      const float* qq = &qk[(hh * 48) * 16 + t1];
      const float* kk = &qk[3072 + (hh * 48) * 16 + t2];
      float sv = 0.f;
#pragma unroll
      for (int d = 0; d < 48; ++d) sv = fmaf(qq[d * 16], kk[d * 16], sv);
      scr[(hhl * 16 + t1) * 17 + t2] = sv * scale;
    }
    __syncthreads();
    if (tid < 128) {
      int rrow = tid >> 2, i = tid & 3;
      const float* row = &scr[rrow * 17 + i * 4];
      float v0 = row[0], v1 = row[1], v2 = row[2], v3 = row[3];
      float m = fmaxf(fmaxf(v0, v1), fmaxf(v2, v3));
      m = fmaxf(m, __shfl_xor(m, 1));
      m = fmaxf(m, __shfl_xor(m, 2));
      float e0 = __expf(v0 - m), e1 = __expf(v1 - m);
      float e2 = __expf(v2 - m), e3 = __expf(v3 - m);
      float s = e0 + e1 + e2 + e3;
      s += __shfl_xor(s, 1);
      s += __shfl_xor(s, 2);
      float inv = 1.f / s;
      float* pd = &qk[(p * 32 + rrow) * 17 + i * 4];
      pd[0] = e0 * inv; pd[1] = e1 * inv; pd[2] = e2 * inv; pd[3] = e3 * inv;
    }
    __syncthreads();
  }

  // stage V: v GEMM (rows 384..575 of w_qkv, K=192) -> qk[3072 + (j-384)*16]
  {
    int j0 = 384 + 3 * ju;
    gemm3<48>(w_qkv + (size_t)j0 * 192, 192, b_qkv + j0,
              xnb, &qk[3072 + (3 * ju) * 16], 16, 4, kp);
  }
  __syncthreads();

  // stage H: attn-out[c][t] = sum_t2 P[h(c)][t][t2] * v[c][t2]  -> xnb (xn dead)
  for (int r = 0; r < 12; ++r) {
    int idx = r * 256 + tid;  // < 3072
    int cc = idx >> 4, t = idx & 15;
    const float* pr = &qk[((cc / 48) * 16 + t) * 17];
    const float* vr = &qk[3072 + cc * 16];
    float sv = 0.f;
#pragma unroll
    for (int t2 = 0; t2 < 16; ++t2) sv = fmaf(pr[t2], vr[t2], sv);
    xnb[cc * 16 + t] = sv;
  }
  __syncthreads();

  // stage I: out proj (192 rows, K=192) -> amap (raw, pre-GN), f32 NCHW
  gemm3<48>(w_proj + (size_t)(3 * ju) * 192, 192, b_proj + 3 * ju,
            xnb, amap + (size_t)(b * CH + 3 * ju) * HW + pix0, HW, W_IMG, kp);
}

// ---------------------------------------------------------------- k4: GN stats (sum, sum2) per (b, group)
__global__ __launch_bounds__(256) void k4_stats(
    const float* __restrict__ src, float* __restrict__ stats)
{
  __shared__ float lds[8];
  int blk = blockIdx.x;             // 24576 = 1536 bc * 16 chunks
  int chunk = blk & 15, bc = blk >> 4;
  int b = bc / 192, cch = bc % 192;
  const float4 v = *(const float4*)(src + (size_t)bc * HW + chunk * 1024 + threadIdx.x * 4);
  float s  = v.x + v.y + v.z + v.w;
  float s2 = v.x * v.x + v.y * v.y + v.z * v.z + v.w * v.w;
  blockReduce2(s, s2, lds);
  if (threadIdx.x == 0) {
    atomicAdd(&stats[(b * 8 + cch / 24) * 2],     s);
    atomicAdd(&stats[(b * 8 + cch / 24) * 2 + 1], s2);
  }
}

// ---------------------------------------------------------------- k4b: per-(b,c) GN scale/shift for amap
__global__ __launch_bounds__(256) void k4b_scale(
    const float* __restrict__ stats, const float* __restrict__ gn_g,
    const float* __restrict__ gn_b, float* __restrict__ scaleS, float* __restrict__ shiftS)
{
  int idx = blockIdx.x * 256 + threadIdx.x;
  if (idx >= 1536) return;
  int b = idx / 192, cch = idx % 192, g = cch / 24;
  float n = 24.f * HW;
  float mu  = stats[(b * 8 + g) * 2] / n;
  float var = stats[(b * 8 + g) * 2 + 1] / n - mu * mu;
  float rs = rsqrtf(fmaxf(var, 0.f) + EPS);
  float scl = rs * gn_g[cch];
  scaleS[idx] = scl;
  shiftS[idx] = gn_b[cch] - mu * scl;
}

// ---------------------------------------------------------------- k6: gates GEMM (+folded GN) + LSTM
__global__ __launch_bounds__(256) void k6_gates(
    float* __restrict__ outp,            // hnext region == amap (in), hnext-pre (out)
    const float* __restrict__ wT,        // [c][row] 192x768
    const float* __restrict__ b_g, const float* __restrict__ cin,
    const float* __restrict__ scaleS, const float* __restrict__ shiftS)
{
  __shared__ float tile[192 * 64];   // 48 KB, [c][p] normalized amap
  const int tid = threadIdx.x;
  const int b  = blockIdx.x >> 8;            // 2048 blocks = 8 b x 256
  const int s0 = (blockIdx.x & 255) * 64;
  float* cout = outp + (size_t)P_TOT * CH;

  for (int idx = tid; idx < 12288; idx += 256) {
    int c = idx >> 6, p = idx & 63;
    float raw = outp[(size_t)(b * CH + c) * HW + s0 + p];
    tile[idx] = fmaf(raw, scaleS[b * CH + c], shiftS[b * CH + c]);
  }
  __syncthreads();

  const int lane = tid & 63;
  const int wv = __builtin_amdgcn_readfirstlane(tid >> 6);

  for (int jg = wv * 6; jg < wv * 6 + 6; ++jg) {
    const int j0 = jg * 8;
    float acc[32];
#pragma unroll
    for (int k = 0; k < 4; ++k)
#pragma unroll
      for (int r = 0; r < 8; ++r) acc[k * 8 + r] = b_g[k * 192 + j0 + r];
#pragma unroll 2
    for (int c = 0; c < 192; ++c) {
      float a = tile[c * 64 + lane];
      const float* wc = wT + (size_t)c * 768 + j0;
#pragma unroll
      for (int k = 0; k < 4; ++k)
#pragma unroll
        for (int r = 0; r < 8; ++r)
          acc[k * 8 + r] = fmaf(a, wc[k * 192 + r], acc[k * 8 + r]);
    }
#pragma unroll
    for (int r = 0; r < 8; ++r) {
      size_t base = (size_t)(b * CH + j0 + r) * HW + s0 + lane;
      float ci = acc[r], cf = acc[8 + r], co = acc[16 + r], cg = acc[24 + r];
      float iv = 1.f / (1.f + __expf(-ci));
      float fv = 1.f / (1.f + __expf(-cf));
      float ov = 1.f / (1.f + __expf(-co));
      float gv = 1.f - 2.f / (__expf(2.f * cg) + 1.f);
      float cn = fmaf(fv, cin[base], iv * gv);
      cout[base] = cn;                                   // cnext (final)
      float th = 1.f - 2.f / (__expf(2.f * cn) + 1.f);
      outp[base] = ov * th;                              // hnext pre-GN
    }
  }
}

// ---------------------------------------------------------------- k7: GN(hnext) in place
__global__ __launch_bounds__(256) void k7_hnext(
    const float* __restrict__ stats2,
    const float* __restrict__ gn_g, const float* __restrict__ gn_b,
    float* __restrict__ outp)
{
  int blk = blockIdx.x;
  int chunk = blk & 15, bc = blk >> 4;
  int b = bc / 192, cch = bc % 192, g = cch / 24;
  float n = 24.f * HW;
  float mu  = stats2[(b * 8 + g) * 2] / n;
  float var = stats2[(b * 8 + g) * 2 + 1] / n - mu * mu;
  float rs = rsqrtf(fmaxf(var, 0.f) + EPS);
  float scl = rs * gn_g[cch];
  float shf = gn_b[cch] - mu * scl;
  float* p = outp + (size_t)bc * HW + chunk * 1024 + threadIdx.x * 4;
  float4 v = *(float4*)p;
  v.x = fmaf(v.x, scl, shf); v.y = fmaf(v.y, scl, shf);
  v.z = fmaf(v.z, scl, shf); v.w = fmaf(v.w, scl, shf);
  *(float4*)p = v;
}

// ---------------------------------------------------------------- launch
extern "C" void kernel_launch(void* const* d_in, const int* in_sizes, int n_in,
                              void* d_out, int out_size, void* d_ws, size_t ws_size,
                              hipStream_t stream) {
  (void)in_sizes; (void)n_in; (void)out_size; (void)ws_size;
  const float* x      = (const float*)d_in[0];
  const float* h      = (const float*)d_in[1];
  const float* c      = (const float*)d_in[2];
  const float* w_in   = (const float*)d_in[3];
  const float* b_in   = (const float*)d_in[4];
  const float* ln_g   = (const float*)d_in[5];
  const float* ln_b   = (const float*)d_in[6];
  const float* w_qkv  = (const float*)d_in[7];
  const float* b_qkv  = (const float*)d_in[8];
  const float* w_proj = (const float*)d_in[9];
  const float* b_proj = (const float*)d_in[10];
  const float* gn_g   = (const float*)d_in[11];
  const float* gn_b   = (const float*)d_in[12];
  const float* w_g    = (const float*)d_in[13];
  const float* b_g    = (const float*)d_in[14];
  float* outp = (float*)d_out;
  char* ws = (char*)d_ws;
  // workspace: 603,136 B total
  float* wT     = (float*)ws;                   // 589,824 B
  float* statsA = (float*)(ws + 589824);        // 512 B
  float* stats2 = (float*)(ws + 590336);        // 512 B
  float* scaleS = (float*)(ws + 590848);        // 6,144 B
  float* shiftS = (float*)(ws + 596992);        // 6,144 B

  hipMemsetAsync(statsA, 0, 1024, stream);      // statsA + stats2

  k0_prep  <<<576, 256, 0, stream>>>(w_g, wT);
  k3_fused <<<8192, 256, 0, stream>>>(x, h, w_in, b_in, ln_g, ln_b,
                                      w_qkv, b_qkv, w_proj, b_proj, outp);
  k4_stats <<<24576, 256, 0, stream>>>(outp, statsA);
  k4b_scale<<<6, 256, 0, stream>>>(statsA, gn_g, gn_b, scaleS, shiftS);
  k6_gates <<<2048, 256, 0, stream>>>(outp, wT, b_g, c, scaleS, shiftS);
  k4_stats <<<24576, 256, 0, stream>>>(outp, stats2);
  k7_hnext <<<24576, 256, 0, stream>>>(stats2, gn_g, gn_b, outp);
}